// Round 7
// baseline (14.001 us; speedup 1.0000x reference)
//
#include <hip/hip_runtime.h>
#include <hip/hip_bf16.h>

// out[n] = b + sum_{i0..i3} W[((i0*8+i1)*8+i2)*8+i3] * P_i0(x0)..P_i3(x3)
// c=(i0*8+i1), j=(i2*8+i3):  G[c][n] = sum_j W2[c][j] * f23[n][j]
//                            out[n]  = sum_c p0[c>>3]*p1[c&7]*G[c][n] + b
//
// R7 floor-probe: NO LDS staging of W, NO __syncthreads. Each lane loads its
// W2 fragment rows directly from global (W = 16 KB -> L1-resident) and packs
// to bf16 in-register. Swapped MFMA (A = W2, B = f23 lane-local) as proven in
// R6; Gt LDS round-trip epilogue as proven in R3/R6. Barrier-free kernel.
// 16 points/wave, 4 lanes/point, 1024 blocks x 256 thr = 16 waves/CU.

typedef short short8 __attribute__((ext_vector_type(8)));
typedef float floatx4 __attribute__((ext_vector_type(4)));

static __device__ inline unsigned short f2bs(float f) {
    return __builtin_bit_cast(unsigned short, __float2bfloat16(f));
}
static __device__ inline unsigned pk(float a, float b) {
    return (unsigned)f2bs(a) | ((unsigned)f2bs(b) << 16);
}

__global__ __launch_bounds__(256, 4) void mvpoly7(
    const float* __restrict__ x,
    const float* __restrict__ W,
    const float* __restrict__ bias,
    float* __restrict__ out,
    int N)
{
    __shared__ float Gt[4][64 * 17];   // per-wave G: addr = c*17 + point (17.4 KB)

    const int tid  = threadIdx.x;
    const int wid  = tid >> 6;
    const int lane = tid & 63;
    const int l15  = lane & 15;
    const int l4   = lane >> 4;

    // ---- x load first (feeds the longest dep chain) ----
    const int pbase = blockIdx.x * 64 + wid * 16;
    int p = pbase + l15;
    if (p >= N) p = N - 1;
    const float4 xv = reinterpret_cast<const float4*>(x)[p];

    // ---- own point's Legendre polys (4x redundant across l4 groups) ----
    float p0[8], p1[8], p2[8], p3[8];
    p0[0] = p1[0] = p2[0] = p3[0] = 1.f;
    p0[1] = xv.x; p1[1] = xv.y; p2[1] = xv.z; p3[1] = xv.w;
    #pragma unroll
    for (int k = 1; k < 7; ++k) {
        const float a = (2.f * k + 1.f) / (float)(k + 1);
        const float c = (float)k / (float)(k + 1);
        p0[k + 1] = a * xv.x * p0[k] - c * p0[k - 1];
        p1[k + 1] = a * xv.y * p1[k] - c * p1[k - 1];
        p2[k + 1] = a * xv.z * p2[k] - c * p2[k - 1];
        p3[k + 1] = a * xv.w * p3[k] - c * p3[k - 1];
    }

    // ---- lane-local B-fragments (f23): B[k = kh*32 + l4*8 + e][col = l15]
    //      = p2[kh*4 + l4] * p3[e] ----
    const float s2a = (l4 == 0) ? p2[0] : (l4 == 1) ? p2[1] : (l4 == 2) ? p2[2] : p2[3];
    const float s2b = (l4 == 0) ? p2[4] : (l4 == 1) ? p2[5] : (l4 == 2) ? p2[6] : p2[7];
    uint4 fb0, fb1;
    fb0.x = pk(s2a * p3[0], s2a * p3[1]); fb0.y = pk(s2a * p3[2], s2a * p3[3]);
    fb0.z = pk(s2a * p3[4], s2a * p3[5]); fb0.w = pk(s2a * p3[6], s2a * p3[7]);
    fb1.x = pk(s2b * p3[0], s2b * p3[1]); fb1.y = pk(s2b * p3[2], s2b * p3[3]);
    fb1.z = pk(s2b * p3[4], s2b * p3[5]); fb1.w = pk(s2b * p3[6], s2b * p3[7]);
    const short8 bf0 = __builtin_bit_cast(short8, fb0);
    const short8 bf1 = __builtin_bit_cast(short8, fb1);

    // ---- A-fragments (W2 rows) straight from global (L1-hot), pack, MFMA ----
    // A[row = c = mt*16 + l15][k = kh*32 + l4*8 + e] = W[c*64 + kh*32 + l4*8 + e]
    floatx4 acc[4];
    #pragma unroll
    for (int mt = 0; mt < 4; ++mt) {
        const int c = mt * 16 + l15;
        const float4* wr = reinterpret_cast<const float4*>(W + c * 64);
        const float4 a0 = wr[l4 * 2];
        const float4 a1 = wr[l4 * 2 + 1];
        const float4 a2 = wr[8 + l4 * 2];
        const float4 a3 = wr[8 + l4 * 2 + 1];
        uint4 w0, w1;
        w0.x = pk(a0.x, a0.y); w0.y = pk(a0.z, a0.w);
        w0.z = pk(a1.x, a1.y); w0.w = pk(a1.z, a1.w);
        w1.x = pk(a2.x, a2.y); w1.y = pk(a2.z, a2.w);
        w1.z = pk(a3.x, a3.y); w1.w = pk(a3.z, a3.w);
        const short8 wf0 = __builtin_bit_cast(short8, w0);
        const short8 wf1 = __builtin_bit_cast(short8, w1);
        floatx4 a = floatx4{0.f, 0.f, 0.f, 0.f};
        a = __builtin_amdgcn_mfma_f32_16x16x32_bf16(wf0, bf0, a, 0, 0, 0);
        a = __builtin_amdgcn_mfma_f32_16x16x32_bf16(wf1, bf1, a, 0, 0, 0);
        acc[mt] = a;
    }

    // ---- G -> per-wave LDS: lane holds D[c = mt*16 + l4*4 + q][point l15] ----
    float* gt = Gt[wid];
    #pragma unroll
    for (int mt = 0; mt < 4; ++mt) {
        #pragma unroll
        for (int q = 0; q < 4; ++q) {
            gt[(mt * 16 + l4 * 4 + q) * 17 + l15] = acc[mt][q];
        }
    }
    // (wave-local region; per-wave in-order DS pipeline orders write->read)

    // ---- epilogue: lane reduces c in [l4*16, l4*16+16) for its point l15 ----
    // i0 = c>>3 = l4*2 + (cc>>3); i1 = c&7 = cc&7
    const float s0a = (l4 == 0) ? p0[0] : (l4 == 1) ? p0[2] : (l4 == 2) ? p0[4] : p0[6];
    const float s0b = (l4 == 0) ? p0[1] : (l4 == 1) ? p0[3] : (l4 == 2) ? p0[5] : p0[7];

    float part = 0.f;
    #pragma unroll
    for (int cc = 0; cc < 16; ++cc) {
        const float g  = gt[(l4 * 16 + cc) * 17 + l15];
        const float f0 = (cc < 8) ? s0a : s0b;
        part = fmaf(g * p1[cc & 7], f0, part);
    }
    part += __shfl_xor(part, 16, 64);
    part += __shfl_xor(part, 32, 64);

    if (l4 == 0) {
        const int po = pbase + l15;
        if (po < N) out[po] = part + bias[0];
    }
}

extern "C" void kernel_launch(void* const* d_in, const int* in_sizes, int n_in,
                              void* d_out, int out_size, void* d_ws, size_t ws_size,
                              hipStream_t stream) {
    const float* x = (const float*)d_in[0];
    const float* W = (const float*)d_in[1];
    const float* b = (const float*)d_in[2];
    float* out = (float*)d_out;

    const int N = in_sizes[0] / 4;          // 65536 points
    const int grid = (N + 63) / 64;         // 64 points per 256-thread block

    hipLaunchKernelGGL(mvpoly7, dim3(grid), dim3(256), 0, stream,
                       x, W, b, out, N);
}

// Round 8
// 9.718 us; speedup vs baseline: 1.4407x; 1.4407x over previous
//
#include <hip/hip_runtime.h>
#include <hip/hip_bf16.h>

// out[n] = b + sum_{i0..i3} W[((i0*8+i1)*8+i2)*8+i3] * P_i0(x0)..P_i3(x3)
// c=(i0*8+i1), j=(i2*8+i3):  G[c][n] = sum_j W2[c][j] * f23[n][j]
//                            out[n]  = sum_c p0[c>>3]*p1[c&7]*G[c][n] + b
//
// R8 = R6 (best: 9.74 us) with the Gt round-trip vectorized:
// Gt laid out [point][c] (stride 68 floats -> 16B-aligned float4 slots,
// 272B point-stride = 4-bank offset per lane -> <=2-way aliasing, free).
// Write: acc[mt] IS the float4 for c = mt*16+l4*4..+3 of point l15.
// Read: 4x ds_read_b128 gives the lane its point's c-quarter [l4*16, +16).
// 32 scalar DS ops -> 8 vector DS ops. Everything else identical to R6.
// 16 points/wave, 4 lanes/point, 1024 blocks x 256 thr = 16 waves/CU.

typedef short short8 __attribute__((ext_vector_type(8)));
typedef float floatx4 __attribute__((ext_vector_type(4)));

static __device__ inline unsigned short f2bs(float f) {
    return __builtin_bit_cast(unsigned short, __float2bfloat16(f));
}
static __device__ inline unsigned pk(float a, float b) {
    return (unsigned)f2bs(a) | ((unsigned)f2bs(b) << 16);
}

__global__ __launch_bounds__(256, 4) void mvpoly8(
    const float* __restrict__ x,
    const float* __restrict__ W,
    const float* __restrict__ bias,
    float* __restrict__ out,
    int N)
{
    __shared__ uint4 Wb[64 * 8];        // W2 bf16 [row c][8 chunks], chunk ^= (c&7)
    __shared__ float Gt[4][16 * 68];    // per-wave G: addr = point*68 + c (17 KB)

    const int tid  = threadIdx.x;
    const int wid  = tid >> 6;
    const int lane = tid & 63;
    const int l15  = lane & 15;
    const int l4   = lane >> 4;

    // ---- x load first (feeds the critical chain) ----
    const int pbase = blockIdx.x * 64 + wid * 16;
    int p = pbase + l15;
    if (p >= N) p = N - 1;
    const float4 xv = reinterpret_cast<const float4*>(x)[p];

    // ---- stage W -> LDS bf16 (block-cooperative) ----
    {
        const int c  = tid >> 2;
        const int j0 = (tid & 3) * 16;
        const float4* ws = reinterpret_cast<const float4*>(W + c * 64 + j0);
        float4 w0 = ws[0], w1 = ws[1], w2 = ws[2], w3 = ws[3];
        uint4 ch0, ch1;
        ch0.x = pk(w0.x, w0.y); ch0.y = pk(w0.z, w0.w);
        ch0.z = pk(w1.x, w1.y); ch0.w = pk(w1.z, w1.w);
        ch1.x = pk(w2.x, w2.y); ch1.y = pk(w2.z, w2.w);
        ch1.z = pk(w3.x, w3.y); ch1.w = pk(w3.z, w3.w);
        const int sw = c & 7;
        Wb[c * 8 + (((j0 >> 3) + 0) ^ sw)] = ch0;
        Wb[c * 8 + (((j0 >> 3) + 1) ^ sw)] = ch1;
    }

    // ---- own point's Legendre polys (4x redundant across l4 groups) ----
    float p0[8], p1[8], p2[8], p3[8];
    p0[0] = p1[0] = p2[0] = p3[0] = 1.f;
    p0[1] = xv.x; p1[1] = xv.y; p2[1] = xv.z; p3[1] = xv.w;
    #pragma unroll
    for (int k = 1; k < 7; ++k) {
        const float a = (2.f * k + 1.f) / (float)(k + 1);
        const float c = (float)k / (float)(k + 1);
        p0[k + 1] = a * xv.x * p0[k] - c * p0[k - 1];
        p1[k + 1] = a * xv.y * p1[k] - c * p1[k - 1];
        p2[k + 1] = a * xv.z * p2[k] - c * p2[k - 1];
        p3[k + 1] = a * xv.w * p3[k] - c * p3[k - 1];
    }

    // ---- lane-local B-fragments (f23): B[k = kh*32 + l4*8 + e][col = l15]
    //      = p2[kh*4 + l4] * p3[e] ----
    const float s2a = (l4 == 0) ? p2[0] : (l4 == 1) ? p2[1] : (l4 == 2) ? p2[2] : p2[3];
    const float s2b = (l4 == 0) ? p2[4] : (l4 == 1) ? p2[5] : (l4 == 2) ? p2[6] : p2[7];
    uint4 fb0, fb1;
    fb0.x = pk(s2a * p3[0], s2a * p3[1]); fb0.y = pk(s2a * p3[2], s2a * p3[3]);
    fb0.z = pk(s2a * p3[4], s2a * p3[5]); fb0.w = pk(s2a * p3[6], s2a * p3[7]);
    fb1.x = pk(s2b * p3[0], s2b * p3[1]); fb1.y = pk(s2b * p3[2], s2b * p3[3]);
    fb1.z = pk(s2b * p3[4], s2b * p3[5]); fb1.w = pk(s2b * p3[6], s2b * p3[7]);
    const short8 bf0 = __builtin_bit_cast(short8, fb0);
    const short8 bf1 = __builtin_bit_cast(short8, fb1);

    __syncthreads();   // Wb ready

    // ---- A-fragments (W2 rows c) from LDS + MFMA: D[row=c][col=point] ----
    floatx4 acc[4];
    #pragma unroll
    for (int mt = 0; mt < 4; ++mt) {
        const int c  = mt * 16 + l15;
        const int sw = c & 7;
        const short8 wf0 = *reinterpret_cast<const short8*>(&Wb[c * 8 + ((0 + l4) ^ sw)]);
        const short8 wf1 = *reinterpret_cast<const short8*>(&Wb[c * 8 + ((4 + l4) ^ sw)]);
        floatx4 a = floatx4{0.f, 0.f, 0.f, 0.f};
        a = __builtin_amdgcn_mfma_f32_16x16x32_bf16(wf0, bf0, a, 0, 0, 0);
        a = __builtin_amdgcn_mfma_f32_16x16x32_bf16(wf1, bf1, a, 0, 0, 0);
        acc[mt] = a;
    }

    // ---- G -> per-wave LDS, vectorized: lane holds D[c = mt*16+l4*4+q][pt l15]
    //      -> float4 store at Gt[l15*68 + mt*16 + l4*4] (16B aligned) ----
    float* gt = Gt[wid];
    #pragma unroll
    for (int mt = 0; mt < 4; ++mt) {
        *reinterpret_cast<float4*>(&gt[l15 * 68 + mt * 16 + l4 * 4]) =
            __builtin_bit_cast(float4, acc[mt]);
    }
    // (wave-local region; per-wave in-order DS pipeline orders write->read)

    // ---- epilogue: lane reduces c in [l4*16, l4*16+16) for its point l15 ----
    // i0 = c>>3 = l4*2 + (cc>>3); i1 = c&7 = cc&7
    const float s0a = (l4 == 0) ? p0[0] : (l4 == 1) ? p0[2] : (l4 == 2) ? p0[4] : p0[6];
    const float s0b = (l4 == 0) ? p0[1] : (l4 == 1) ? p0[3] : (l4 == 2) ? p0[5] : p0[7];

    const float4 r0 = *reinterpret_cast<const float4*>(&gt[l15 * 68 + l4 * 16 + 0]);
    const float4 r1 = *reinterpret_cast<const float4*>(&gt[l15 * 68 + l4 * 16 + 4]);
    const float4 r2 = *reinterpret_cast<const float4*>(&gt[l15 * 68 + l4 * 16 + 8]);
    const float4 r3 = *reinterpret_cast<const float4*>(&gt[l15 * 68 + l4 * 16 + 12]);

    float inA = 0.f, inB = 0.f;
    inA = fmaf(r0.x, p1[0], inA); inA = fmaf(r0.y, p1[1], inA);
    inA = fmaf(r0.z, p1[2], inA); inA = fmaf(r0.w, p1[3], inA);
    inA = fmaf(r1.x, p1[4], inA); inA = fmaf(r1.y, p1[5], inA);
    inA = fmaf(r1.z, p1[6], inA); inA = fmaf(r1.w, p1[7], inA);
    inB = fmaf(r2.x, p1[0], inB); inB = fmaf(r2.y, p1[1], inB);
    inB = fmaf(r2.z, p1[2], inB); inB = fmaf(r2.w, p1[3], inB);
    inB = fmaf(r3.x, p1[4], inB); inB = fmaf(r3.y, p1[5], inB);
    inB = fmaf(r3.z, p1[6], inB); inB = fmaf(r3.w, p1[7], inB);

    float part = s0a * inA + s0b * inB;
    part += __shfl_xor(part, 16, 64);
    part += __shfl_xor(part, 32, 64);

    if (l4 == 0) {
        const int po = pbase + l15;
        if (po < N) out[po] = part + bias[0];
    }
}

extern "C" void kernel_launch(void* const* d_in, const int* in_sizes, int n_in,
                              void* d_out, int out_size, void* d_ws, size_t ws_size,
                              hipStream_t stream) {
    const float* x = (const float*)d_in[0];
    const float* W = (const float*)d_in[1];
    const float* b = (const float*)d_in[2];
    float* out = (float*)d_out;

    const int N = in_sizes[0] / 4;          // 65536 points
    const int grid = (N + 63) / 64;         // 64 points per 256-thread block

    hipLaunchKernelGGL(mvpoly8, dim3(grid), dim3(256), 0, stream,
                       x, W, b, out, N);
}